// Round 7
// baseline (572.642 us; speedup 1.0000x reference)
//
#include <hip/hip_runtime.h>

typedef float vfloat4 __attribute__((ext_vector_type(4)));

#define TT 1024
#define BB 8
#define DD 16
#define NN 8192   // BB*TT

__device__ inline float untr(unsigned u) {
    unsigned b = (u & 0x80000000u) ? (u & 0x7fffffffu) : ~u;
    return __uint_as_float(b);
}
__device__ inline unsigned tr(float f) {
    unsigned b = __float_as_uint(f);
    return (b & 0x80000000u) ? ~b : (b | 0x80000000u);
}

// ---- Kernel A: per-column median (3-pass radix select) + fused colsum ------
// Block d: finds thr[d] exactly, then computes per-q sums of m, m*z, m*z^2
// using the keys already in LDS (m via order-preserving key compare) and
// writes them TRANSPOSED [d][q] so scale_k's loads coalesce.
// Also zeroes Sacc/nacc (stream-ordered before scale_k's atomics).
__global__ __launch_bounds__(1024) void median_k(const float* __restrict__ v,
                                                 const float* __restrict__ z,
                                                 float* __restrict__ thr,
                                                 float* __restrict__ Sacc,
                                                 float* __restrict__ nacc,
                                                 float* __restrict__ ms_t,
                                                 float* __restrict__ vs_t,
                                                 float* __restrict__ us_t) {
    __shared__ unsigned key[NN];      // 32 KB
    __shared__ unsigned hist[2048];   // 8 KB
    __shared__ unsigned wsum[16];
    __shared__ unsigned found_bin, found_cum;
    __shared__ unsigned s_cle, s_min, s_keythr;
    const int d = blockIdx.x;
    const int tid = threadIdx.x;
    const int wid = tid >> 6, lane = tid & 63;

    if (tid == 0) { Sacc[d] = 0.f; nacc[d] = 0.f; }

    for (int i = tid; i < NN; i += 1024)
        key[i] = tr(v[i * DD + d]);           // order-preserving transform
    if (tid == 0) { s_cle = 0; s_min = 0xFFFFFFFFu; }
    __syncthreads();

    unsigned prefix = 0;
    unsigned r = 4095;            // 0-based rank of lower middle
    int matched_bits = 0;
    int shift = 32;
    const int chunk_bits[3] = {11, 11, 10};
#pragma unroll
    for (int pass = 0; pass < 3; ++pass) {
        const int bits = chunk_bits[pass];
        shift -= bits;
        const int nb = 1 << bits;
        hist[tid] = 0; hist[tid + 1024] = 0;
        __syncthreads();
        for (int i = tid; i < NN; i += 1024) {
            unsigned k = key[i];
            if (matched_bits == 0 || (k >> (shift + bits)) == prefix)
                atomicAdd(&hist[(k >> shift) & (unsigned)(nb - 1)], 1u);
        }
        __syncthreads();
        unsigned h0 = 0, h1 = 0, s2 = 0;
        if (tid < nb / 2) { h0 = hist[2 * tid]; h1 = hist[2 * tid + 1]; s2 = h0 + h1; }
        unsigned inc = s2;
        for (int o = 1; o < 64; o <<= 1) {
            unsigned t = __shfl_up(inc, o);
            if (lane >= o) inc += t;
        }
        if (lane == 63) wsum[wid] = inc;
        __syncthreads();
        if (tid < 16) {
            unsigned x = wsum[tid], ix = x;
            for (int o = 1; o < 16; o <<= 1) {
                unsigned t = __shfl_up(ix, o);
                if (lane >= o) ix += t;
            }
            wsum[tid] = ix - x;   // exclusive wave offsets
        }
        __syncthreads();
        if (tid < nb / 2) {
            unsigned cum = wsum[wid] + (inc - s2);
            if (r >= cum && r < cum + h0)            { found_bin = 2u * tid;     found_cum = cum; }
            else if (r >= cum + h0 && r < cum + s2)  { found_bin = 2u * tid + 1; found_cum = cum + h0; }
        }
        __syncthreads();
        prefix = (prefix << bits) | found_bin;
        r -= found_cum;
        matched_bits += bits;
    }
    const unsigned A = prefix;     // key of s[4095]

    // second order stat: c_le = #keys<=A ; mg = min key > A
    unsigned cle = 0, mg = 0xFFFFFFFFu;
    for (int i = tid; i < NN; i += 1024) {
        unsigned k = key[i];
        if (k <= A) cle++;
        else mg = min(mg, k);
    }
    for (int o = 32; o; o >>= 1) {
        cle += __shfl_xor(cle, o);
        mg = min(mg, (unsigned)__shfl_xor(mg, o));
    }
    if (lane == 0) { atomicAdd(&s_cle, cle); atomicMin(&s_min, mg); }
    __syncthreads();
    if (tid == 0) {
        unsigned Bk = (s_cle >= 4097u) ? A : s_min;   // s[4096]
        const float th = 0.5f * (untr(A) + untr(Bk));
        thr[d] = th;
        s_keythr = tr(th);        // m = (vf <= th)  <=>  key <= tr(th)
    }
    __syncthreads();

    // ---- fused colsum: thread q sums over b (keys from LDS, z from L2) ----
    const unsigned kt = s_keythr;
    float s_m = 0.f, s_v = 0.f, s_u = 0.f;
#pragma unroll
    for (int b = 0; b < BB; ++b) {
        const unsigned k = key[b * TT + tid];
        const float zz = z[(b * TT + tid) * DD + d];
        if (k <= kt) { s_m += 1.f; s_v += zz; s_u += zz * zz; }
    }
    ms_t[d * TT + tid] = s_m;     // transposed [d][q]: coalesced here & in scale_k
    vs_t[d * TT + tid] = s_v;
    us_t[d * TT + tid] = s_u;
}

// ---- Kernel B: Toeplitz quadratic forms per d ------------------------------
// grid = DD*16 x 64; block: d = bid>>4, p-chunk = bid&15 (1 wave/CU).
__global__ __launch_bounds__(64) void scale_k(const float* __restrict__ ms_t,
                                              const float* __restrict__ vs_t,
                                              const float* __restrict__ us_t,
                                              float* __restrict__ Sacc,
                                              float* __restrict__ nacc) {
    __shared__ float2 smsv[TT];
    __shared__ float wt[TT];
    const int d = blockIdx.x >> 4;
    const int chunk = blockIdx.x & 15;
    const int tid = threadIdx.x;
    for (int q = tid; q < TT; q += 64) {
        smsv[q] = make_float2(ms_t[d * TT + q], vs_t[d * TT + q]);
        wt[q] = 1.0f / ((float)q + 1e-6f);
    }
    __syncthreads();
    const int p = chunk * 64 + tid;
    const float a = us_t[d * TT + p];
    const float c = smsv[p].y;
    float acc = 0.f;
#pragma unroll 4
    for (int q = 0; q < TT; ++q) {
        int ad = p - q; ad = ad < 0 ? -ad : ad;
        const float2 x = smsv[q];
        acc = fmaf(wt[ad], fmaf(a, x.x, -(c * x.y)), acc);
    }
    float npart = smsv[p].x;
    for (int o = 32; o; o >>= 1) {
        acc += __shfl_xor(acc, o);
        npart += __shfl_xor(npart, o);
    }
    if (tid == 0) {
        atomicAdd(&Sacc[d], 2.0f * acc);
        atomicAdd(&nacc[d], npart);
    }
}

// ---- Kernel C: finalize ls inline + stream K out ---------------------------
// out[b][d][i][j] = exp(-(j-i)^2 / ls_d^2).
// 32 consecutive rows (128 KB contiguous) per block, 4096 blocks total:
// 32x fewer dispatches than 1-row blocks, long sequential per-block write
// streams (fill-kernel-like). d and inv_ls2 hoisted (32 | 1024 so the d
// panel never changes within a block).
__global__ __launch_bounds__(256) void write_k(const float* __restrict__ Sacc,
                                               const float* __restrict__ nacc,
                                               const float* __restrict__ lsin,
                                               float* __restrict__ out) {
    const int row0 = blockIdx.x << 5;        // global row = ((b*16+d)*1024+i)
    const int d = (row0 >> 10) & (DD - 1);

    const float n = nacc[d], S = Sacc[d];
    float inv;
    if (n >= 2.0f) inv = (n * n) / S;                 // 1/ls^2
    else { const float e = __expf(lsin[d]); inv = 1.0f / (e * e); }

    const int j0 = threadIdx.x * 4;
    float* base = out + (((size_t)row0) << 10) + (size_t)j0;
#pragma unroll 4
    for (int rr = 0; rr < 32; ++rr) {
        const int i = (row0 + rr) & (TT - 1);
        vfloat4 val;
#pragma unroll
        for (int jj = 0; jj < 4; ++jj) {
            const int diff = (j0 + jj) - i;
            const float f = (float)(diff * diff);
            val[jj] = __expf(-f * inv);
        }
        __builtin_nontemporal_store(val, (vfloat4*)(base + ((size_t)rr << 10)));
    }
}

extern "C" void kernel_launch(void* const* d_in, const int* in_sizes, int n_in,
                              void* d_out, int out_size, void* d_ws, size_t ws_size,
                              hipStream_t stream) {
    const float* z    = (const float*)d_in[0];
    const float* v    = (const float*)d_in[1];
    const float* lsin = (const float*)d_in[2];
    float* out = (float*)d_out;

    float* ws   = (float*)d_ws;
    float* thr  = ws;                 // 16
    float* Sacc = ws + 16;            // 16
    float* nacc = ws + 32;            // 16
    float* ms_t = ws + 64;            // 16384  [d][q]
    float* vs_t = ms_t + TT * DD;     // 16384
    float* us_t = vs_t + TT * DD;     // 16384

    median_k<<<DD, 1024, 0, stream>>>(v, z, thr, Sacc, nacc, ms_t, vs_t, us_t);
    scale_k<<<DD * 16, 64, 0, stream>>>(ms_t, vs_t, us_t, Sacc, nacc);
    write_k<<<(BB * DD * TT) / 32, 256, 0, stream>>>(Sacc, nacc, lsin, out);
}

// Round 8
// 554.767 us; speedup vs baseline: 1.0322x; 1.0322x over previous
//
#include <hip/hip_runtime.h>

typedef float vfloat4 __attribute__((ext_vector_type(4)));

#define TT 1024
#define BB 8
#define DD 16
#define NN 8192   // BB*TT

__device__ inline float untr(unsigned u) {
    unsigned b = (u & 0x80000000u) ? (u & 0x7fffffffu) : ~u;
    return __uint_as_float(b);
}
__device__ inline unsigned tr(float f) {
    unsigned b = __float_as_uint(f);
    return (b & 0x80000000u) ? ~b : (b | 0x80000000u);
}

// ---- Kernel A: per-column median (3-pass radix select) + fused colsum ------
// Block d: finds thr[d] exactly, then computes per-q sums of m, m*z, m*z^2
// using the keys already in LDS (m via order-preserving key compare) and
// writes them TRANSPOSED [d][q] so scale_k's loads coalesce.
// Also zeroes Sacc/nacc (stream-ordered before scale_k's atomics).
__global__ __launch_bounds__(1024) void median_k(const float* __restrict__ v,
                                                 const float* __restrict__ z,
                                                 float* __restrict__ thr,
                                                 float* __restrict__ Sacc,
                                                 float* __restrict__ nacc,
                                                 float* __restrict__ ms_t,
                                                 float* __restrict__ vs_t,
                                                 float* __restrict__ us_t) {
    __shared__ unsigned key[NN];      // 32 KB
    __shared__ unsigned hist[2048];   // 8 KB
    __shared__ unsigned wsum[16];
    __shared__ unsigned found_bin, found_cum;
    __shared__ unsigned s_cle, s_min, s_keythr;
    const int d = blockIdx.x;
    const int tid = threadIdx.x;
    const int wid = tid >> 6, lane = tid & 63;

    if (tid == 0) { Sacc[d] = 0.f; nacc[d] = 0.f; }

    for (int i = tid; i < NN; i += 1024)
        key[i] = tr(v[i * DD + d]);           // order-preserving transform
    if (tid == 0) { s_cle = 0; s_min = 0xFFFFFFFFu; }
    __syncthreads();

    unsigned prefix = 0;
    unsigned r = 4095;            // 0-based rank of lower middle
    int matched_bits = 0;
    int shift = 32;
    const int chunk_bits[3] = {11, 11, 10};
#pragma unroll
    for (int pass = 0; pass < 3; ++pass) {
        const int bits = chunk_bits[pass];
        shift -= bits;
        const int nb = 1 << bits;
        hist[tid] = 0; hist[tid + 1024] = 0;
        __syncthreads();
        for (int i = tid; i < NN; i += 1024) {
            unsigned k = key[i];
            if (matched_bits == 0 || (k >> (shift + bits)) == prefix)
                atomicAdd(&hist[(k >> shift) & (unsigned)(nb - 1)], 1u);
        }
        __syncthreads();
        unsigned h0 = 0, h1 = 0, s2 = 0;
        if (tid < nb / 2) { h0 = hist[2 * tid]; h1 = hist[2 * tid + 1]; s2 = h0 + h1; }
        unsigned inc = s2;
        for (int o = 1; o < 64; o <<= 1) {
            unsigned t = __shfl_up(inc, o);
            if (lane >= o) inc += t;
        }
        if (lane == 63) wsum[wid] = inc;
        __syncthreads();
        if (tid < 16) {
            unsigned x = wsum[tid], ix = x;
            for (int o = 1; o < 16; o <<= 1) {
                unsigned t = __shfl_up(ix, o);
                if (lane >= o) ix += t;
            }
            wsum[tid] = ix - x;   // exclusive wave offsets
        }
        __syncthreads();
        if (tid < nb / 2) {
            unsigned cum = wsum[wid] + (inc - s2);
            if (r >= cum && r < cum + h0)            { found_bin = 2u * tid;     found_cum = cum; }
            else if (r >= cum + h0 && r < cum + s2)  { found_bin = 2u * tid + 1; found_cum = cum + h0; }
        }
        __syncthreads();
        prefix = (prefix << bits) | found_bin;
        r -= found_cum;
        matched_bits += bits;
    }
    const unsigned A = prefix;     // key of s[4095]

    // second order stat: c_le = #keys<=A ; mg = min key > A
    unsigned cle = 0, mg = 0xFFFFFFFFu;
    for (int i = tid; i < NN; i += 1024) {
        unsigned k = key[i];
        if (k <= A) cle++;
        else mg = min(mg, k);
    }
    for (int o = 32; o; o >>= 1) {
        cle += __shfl_xor(cle, o);
        mg = min(mg, (unsigned)__shfl_xor(mg, o));
    }
    if (lane == 0) { atomicAdd(&s_cle, cle); atomicMin(&s_min, mg); }
    __syncthreads();
    if (tid == 0) {
        unsigned Bk = (s_cle >= 4097u) ? A : s_min;   // s[4096]
        const float th = 0.5f * (untr(A) + untr(Bk));
        thr[d] = th;
        s_keythr = tr(th);        // m = (vf <= th)  <=>  key <= tr(th)
    }
    __syncthreads();

    // ---- fused colsum: thread q sums over b (keys from LDS, z from L2) ----
    const unsigned kt = s_keythr;
    float s_m = 0.f, s_v = 0.f, s_u = 0.f;
#pragma unroll
    for (int b = 0; b < BB; ++b) {
        const unsigned k = key[b * TT + tid];
        const float zz = z[(b * TT + tid) * DD + d];
        if (k <= kt) { s_m += 1.f; s_v += zz; s_u += zz * zz; }
    }
    ms_t[d * TT + tid] = s_m;     // transposed [d][q]: coalesced here & in scale_k
    vs_t[d * TT + tid] = s_v;
    us_t[d * TT + tid] = s_u;
}

// ---- Kernel B: Toeplitz quadratic forms per d ------------------------------
// grid = DD*16 x 64; block: d = bid>>4, p-chunk = bid&15 (1 wave/CU).
__global__ __launch_bounds__(64) void scale_k(const float* __restrict__ ms_t,
                                              const float* __restrict__ vs_t,
                                              const float* __restrict__ us_t,
                                              float* __restrict__ Sacc,
                                              float* __restrict__ nacc) {
    __shared__ float2 smsv[TT];
    __shared__ float wt[TT];
    const int d = blockIdx.x >> 4;
    const int chunk = blockIdx.x & 15;
    const int tid = threadIdx.x;
    for (int q = tid; q < TT; q += 64) {
        smsv[q] = make_float2(ms_t[d * TT + q], vs_t[d * TT + q]);
        wt[q] = 1.0f / ((float)q + 1e-6f);
    }
    __syncthreads();
    const int p = chunk * 64 + tid;
    const float a = us_t[d * TT + p];
    const float c = smsv[p].y;
    float acc = 0.f;
#pragma unroll 4
    for (int q = 0; q < TT; ++q) {
        int ad = p - q; ad = ad < 0 ? -ad : ad;
        const float2 x = smsv[q];
        acc = fmaf(wt[ad], fmaf(a, x.x, -(c * x.y)), acc);
    }
    float npart = smsv[p].x;
    for (int o = 32; o; o >>= 1) {
        acc += __shfl_xor(acc, o);
        npart += __shfl_xor(npart, o);
    }
    if (tid == 0) {
        atomicAdd(&Sacc[d], 2.0f * acc);
        atomicAdd(&nacc[d], npart);
    }
}

// ---- Kernel C: finalize ls inline + stream K out ---------------------------
// out[b][d][i][j] = exp(-(j-i)^2 / ls_d^2).
// ONE contiguous 4 KB row per block: bid -> (b,d,i); consecutive bids walk
// consecutive rows of the same (b,d) panel -> near-sequential device-wide
// write pattern. Best-measured configuration (R6: 555.9 us).
__global__ __launch_bounds__(256) void write_k(const float* __restrict__ Sacc,
                                               const float* __restrict__ nacc,
                                               const float* __restrict__ lsin,
                                               float* __restrict__ out) {
    const int bid = blockIdx.x;              // bid = ((b*16 + d)*1024 + i)
    const int r = bid & 16383;
    const int d = r >> 10;
    const int i = r & (TT - 1);

    const float n = nacc[d], S = Sacc[d];
    float inv;
    if (n >= 2.0f) inv = (n * n) / S;                 // 1/ls^2
    else { const float e = __expf(lsin[d]); inv = 1.0f / (e * e); }

    const int j0 = threadIdx.x * 4;
    vfloat4 val;
#pragma unroll
    for (int jj = 0; jj < 4; ++jj) {
        const int diff = (j0 + jj) - i;
        const float f = (float)(diff * diff);
        val[jj] = __expf(-f * inv);
    }
    vfloat4* p = (vfloat4*)(out + (((size_t)bid) << 10) + (size_t)j0);
    __builtin_nontemporal_store(val, p);
}

extern "C" void kernel_launch(void* const* d_in, const int* in_sizes, int n_in,
                              void* d_out, int out_size, void* d_ws, size_t ws_size,
                              hipStream_t stream) {
    const float* z    = (const float*)d_in[0];
    const float* v    = (const float*)d_in[1];
    const float* lsin = (const float*)d_in[2];
    float* out = (float*)d_out;

    float* ws   = (float*)d_ws;
    float* thr  = ws;                 // 16
    float* Sacc = ws + 16;            // 16
    float* nacc = ws + 32;            // 16
    float* ms_t = ws + 64;            // 16384  [d][q]
    float* vs_t = ms_t + TT * DD;     // 16384
    float* us_t = vs_t + TT * DD;     // 16384

    median_k<<<DD, 1024, 0, stream>>>(v, z, thr, Sacc, nacc, ms_t, vs_t, us_t);
    scale_k<<<DD * 16, 64, 0, stream>>>(ms_t, vs_t, us_t, Sacc, nacc);
    write_k<<<BB * DD * TT, 256, 0, stream>>>(Sacc, nacc, lsin, out);
}